// Round 13
// baseline (667.456 us; speedup 1.0000x reference)
//
#include <hip/hip_runtime.h>
#include <hip/hip_bf16.h>
#include <stdint.h>

typedef __attribute__((ext_vector_type(8))) short s16x8;
typedef __attribute__((ext_vector_type(4))) float f32x4;

static constexpr int Bb = 8, Ss = 2048, Ee = 1024, Ff = 4096;
static constexpr int M_TOK = Bb * Ss;                      // 16384
static constexpr size_t OUT_SLOT = (size_t)M_TOK * Ee;     // elements per output tensor

__device__ inline unsigned short f2bf(float f) {
  unsigned int u = __float_as_uint(f);
  unsigned int r = (u + 0x7FFFu + ((u >> 16) & 1u)) >> 16;
  return (unsigned short)r;
}
__device__ inline float bf2f(unsigned short h) {
  return __uint_as_float(((unsigned int)h) << 16);
}

// direct HBM -> LDS, 16B per lane; lds dest = wave-uniform base + lane*16
__device__ inline void gload16(const unsigned short* g, const unsigned short* l) {
  __builtin_amdgcn_global_load_lds(
      (const __attribute__((address_space(1))) void*)g,
      (__attribute__((address_space(3))) void*)(unsigned short*)l, 16, 0, 0);
}

// ---------------- elementwise f32 -> bf16 ----------------
__global__ __launch_bounds__(256) void k_cvt_f32_bf16(const float* __restrict__ in,
                                                      unsigned short* __restrict__ out, int n4) {
  int i = blockIdx.x * blockDim.x + threadIdx.x;
  int stride = gridDim.x * blockDim.x;
  for (; i < n4; i += stride) {
    float4 v = ((const float4*)in)[i];
    ushort4 o;
    o.x = f2bf(v.x); o.y = f2bf(v.y); o.z = f2bf(v.z); o.w = f2bf(v.w);
    ((ushort4*)out)[i] = o;
  }
}

// ---------------- concat 3 bias vectors [1024] -> [3072] ----------------
__global__ __launch_bounds__(256) void k_concat3(const float* __restrict__ a,
                                                 const float* __restrict__ b,
                                                 const float* __restrict__ c,
                                                 float* __restrict__ out) {
  int i = blockIdx.x * 256 + threadIdx.x;
  const float* src = (i < 1024) ? a : (i < 2048) ? b : c;
  out[i] = src[i & 1023];
}

// ---------------- transpose+convert W[R][C] f32 -> WT[C][R] bf16 ----------------
__global__ __launch_bounds__(256) void k_transpose_w(const float* __restrict__ in,
                                                     unsigned short* __restrict__ out,
                                                     int R, int C) {
  __shared__ float t[32][33];
  int c0 = blockIdx.x * 32, r0 = blockIdx.y * 32;
  int tx = threadIdx.x, ty = threadIdx.y;
  for (int i = ty; i < 32; i += 8)
    t[i][tx] = in[(size_t)(r0 + i) * C + c0 + tx];
  __syncthreads();
  for (int i = ty; i < 32; i += 8)
    out[(size_t)(c0 + i) * R + r0 + tx] = f2bf(t[tx][i]);
}

// ---------------- per-batch transpose v[S][E] bf16 -> vT[E][S] bf16 ----------------
__global__ __launch_bounds__(256) void k_transpose_v(const unsigned short* __restrict__ v,
                                                     unsigned short* __restrict__ vT) {
  __shared__ unsigned short t[32][33];
  int b = blockIdx.z;
  const unsigned short* in = v + (size_t)b * Ss * Ee;
  unsigned short* out = vT + (size_t)b * Ee * Ss;
  int c0 = blockIdx.x * 32, r0 = blockIdx.y * 32;  // c over E, r over S
  int tx = threadIdx.x, ty = threadIdx.y;
  for (int i = ty; i < 32; i += 8)
    t[i][tx] = in[(size_t)(r0 + i) * Ee + c0 + tx];
  __syncthreads();
  for (int i = ty; i < 32; i += 8)
    out[(size_t)(c0 + i) * Ss + r0 + tx] = t[tx][i];
}

// ---------------- 256x256 pipelined bf16 GEMM (16x16x32 MFMA) ----------------
// 8 waves (2M x 4N), per-wave 128x64 output (8x4 frags).
// TWOSLOT=false: 4-slot LDS ring (128 KiB, 1 block/CU), counted vmcnt (6|4|0),
//   2 barriers/tile — proven pipeline for compute-long GEMMs.
// TWOSLOT=true: 2-slot ring (64 KiB, 2 blocks/CU), 1 barrier+vmcnt(0)/tile —
//   drain covered by co-resident block; epilogue overlaps next block's K-loop.
//   Used for write-heavy QKV.
// Swizzle: chunk c -> c ^ ((r>>1)&3): measured 0 bank conflicts.
// QKV mode: N=3072 fused q|k|v; epilogue demuxes by col>>10, f32 stores nontemporal.
template <bool TWOSLOT, bool QKV, bool WF32, bool WB16, bool RELU, bool HAS_BIAS>
__global__ __launch_bounds__(512, 2) void k_gemm256(const unsigned short* __restrict__ A,
                                                    const unsigned short* __restrict__ Bt,
                                                    float* __restrict__ Cf,
                                                    unsigned short* __restrict__ Cb,
                                                    const float* __restrict__ bias,
                                                    int M, int N, int K,
                                                    long aBatch, long bBatch, long cBatch,
                                                    float scale) {
  constexpr int NS = TWOSLOT ? 2 : 4;
  __shared__ unsigned short lds[NS][2][256 * 32];  // [slot][A|B] 64 or 128 KiB
  const int tid = threadIdx.x;
  const int lane = tid & 63;
  const int wid = tid >> 6;              // 0..7
  const int wr = wid >> 2, wc = wid & 3; // 2 x 4 wave grid

  // T1 + L2 locality: XCD gets a contiguous chunk of a (4-m-wide, n-fast) global order.
  const int gx = gridDim.x, gy = gridDim.y;
  const int nwg = gx * gy;
  const int id = blockIdx.y * gx + blockIdx.x;
  const int qq = nwg >> 3;
  const int s = (id & 7) * qq + (id >> 3);  // global order index
  const int g4 = s / (gy * 4);
  const int r4 = s - g4 * gy * 4;
  const int m0 = (g4 * 4 + (r4 & 3)) * 256;
  const int n0 = (r4 >> 2) * 256;
  const int z = blockIdx.z;
  A += (size_t)z * aBatch;
  Bt += (size_t)z * bBatch;

  // staging: dest elem = j*4096 + tid*8 -> row = j*128 + tid/4, chunk_dst = tid&3.
  // source chunk = chunk_dst ^ ((row>>1)&3); (row>>1)&3 == (tid>>3)&3 for both j.
  const int srow = tid >> 2;
  const int csrc = (tid & 3) ^ ((tid >> 3) & 3);
  const unsigned short* ga0 = A + (size_t)(m0 + srow) * K + csrc * 8;
  const unsigned short* ga1 = A + (size_t)(m0 + 128 + srow) * K + csrc * 8;
  const unsigned short* gb0 = Bt + (size_t)(n0 + srow) * K + csrc * 8;
  const unsigned short* gb1 = Bt + (size_t)(n0 + 128 + srow) * K + csrc * 8;
  const int waveDst = (wid << 9);  // wave-uniform LDS elem offset; +lane*8 implicit

  auto STAGE_A = [&](int step) {
    const int slot = step & (NS - 1);
    const size_t ko = (size_t)step << 5;
    const unsigned short* la = &lds[slot][0][0];
    gload16(ga0 + ko, la + waveDst);
    gload16(ga1 + ko, la + 4096 + waveDst);
  };
  auto STAGE_B = [&](int step) {
    const int slot = step & (NS - 1);
    const size_t ko = (size_t)step << 5;
    const unsigned short* lb = &lds[slot][1][0];
    gload16(gb0 + ko, lb + waveDst);
    gload16(gb1 + ko, lb + 4096 + waveDst);
  };

  f32x4 acc[8][4] = {};
  const int fr = lane & 15;
  const int cc = ((lane >> 4) ^ ((fr >> 1) & 3)) * 8;  // swizzled chunk elem offset
  const int nt = K >> 5;

  if (TWOSLOT) {
    // -------- 2-slot double-buffer: 1 barrier + vmcnt(0) per tile --------
    STAGE_A(0); STAGE_B(0);
    asm volatile("s_waitcnt vmcnt(0)" ::: "memory");
    __builtin_amdgcn_s_barrier();
    asm volatile("" ::: "memory");
    for (int t = 0; t < nt; ++t) {
      const int slot = t & 1;
      const unsigned short* la = &lds[slot][0][0];
      const unsigned short* lb = &lds[slot][1][0];
      s16x8 ra[4], rb[4], ra2[4];
#pragma unroll
      for (int ni = 0; ni < 4; ++ni)
        rb[ni] = *(const s16x8*)(lb + ((wc * 64 + ni * 16 + fr) * 32 + cc));
#pragma unroll
      for (int mi = 0; mi < 4; ++mi) {
        ra[mi] = *(const s16x8*)(la + ((wr * 128 + mi * 16 + fr) * 32 + cc));
        ra2[mi] = *(const s16x8*)(la + ((wr * 128 + (mi + 4) * 16 + fr) * 32 + cc));
      }
      if (t + 1 < nt) { STAGE_A(t + 1); STAGE_B(t + 1); }
      __builtin_amdgcn_s_setprio(1);
#pragma unroll
      for (int mi = 0; mi < 4; ++mi)
#pragma unroll
        for (int ni = 0; ni < 4; ++ni)
          acc[mi][ni] = __builtin_amdgcn_mfma_f32_16x16x32_bf16(ra[mi], rb[ni], acc[mi][ni], 0, 0, 0);
#pragma unroll
      for (int mi = 0; mi < 4; ++mi)
#pragma unroll
        for (int ni = 0; ni < 4; ++ni)
          acc[mi + 4][ni] = __builtin_amdgcn_mfma_f32_16x16x32_bf16(ra2[mi], rb[ni], acc[mi + 4][ni], 0, 0, 0);
      __builtin_amdgcn_s_setprio(0);
      asm volatile("s_waitcnt vmcnt(0)" ::: "memory");
      __builtin_amdgcn_s_barrier();
      asm volatile("" ::: "memory");
    }
  } else {
    // -------- 4-slot counted pipeline: vmcnt(6|4|0), 2 barriers/tile --------
    STAGE_A(0); STAGE_B(0); STAGE_A(1); STAGE_B(1); STAGE_A(2); STAGE_B(2);
    asm volatile("s_waitcnt vmcnt(8)" ::: "memory");
    __builtin_amdgcn_s_barrier();
    asm volatile("" ::: "memory");

    for (int t = 0; t < nt; ++t) {
      const int slot = t & 3;
      const unsigned short* la = &lds[slot][0][0];
      const unsigned short* lb = &lds[slot][1][0];
      s16x8 ra[4], rb[4], ra2[4];
#pragma unroll
      for (int ni = 0; ni < 4; ++ni)
        rb[ni] = *(const s16x8*)(lb + ((wc * 64 + ni * 16 + fr) * 32 + cc));
#pragma unroll
      for (int mi = 0; mi < 4; ++mi)
        ra[mi] = *(const s16x8*)(la + ((wr * 128 + mi * 16 + fr) * 32 + cc));
      if (t + 3 < nt) {
        STAGE_A(t + 3);
        asm volatile("s_waitcnt vmcnt(6)" ::: "memory");   // tile t+1 fully landed
      } else if (t + 2 < nt) {
        asm volatile("s_waitcnt vmcnt(4)" ::: "memory");
      } else {
        asm volatile("s_waitcnt vmcnt(0)" ::: "memory");
      }
      __builtin_amdgcn_s_barrier();
      asm volatile("" ::: "memory");
      __builtin_amdgcn_s_setprio(1);
#pragma unroll
      for (int mi = 0; mi < 4; ++mi)
#pragma unroll
        for (int ni = 0; ni < 4; ++ni)
          acc[mi][ni] = __builtin_amdgcn_mfma_f32_16x16x32_bf16(ra[mi], rb[ni], acc[mi][ni], 0, 0, 0);
#pragma unroll
      for (int mi = 0; mi < 4; ++mi)
        ra2[mi] = *(const s16x8*)(la + ((wr * 128 + (mi + 4) * 16 + fr) * 32 + cc));
      if (t + 3 < nt) STAGE_B(t + 3);
      __builtin_amdgcn_s_setprio(0);
      __builtin_amdgcn_s_barrier();
      asm volatile("" ::: "memory");
      __builtin_amdgcn_s_setprio(1);
#pragma unroll
      for (int mi = 0; mi < 4; ++mi)
#pragma unroll
        for (int ni = 0; ni < 4; ++ni)
          acc[mi + 4][ni] = __builtin_amdgcn_mfma_f32_16x16x32_bf16(ra2[mi], rb[ni], acc[mi + 4][ni], 0, 0, 0);
      __builtin_amdgcn_s_setprio(0);
    }
  }

  // epilogue: D mapping col=lane&15, row=(lane>>4)*4+reg  [verified m89]
  const int er = lane & 15, eq = lane >> 4;
#pragma unroll
  for (int mi = 0; mi < 8; ++mi) {
#pragma unroll
    for (int ni = 0; ni < 4; ++ni) {
#pragma unroll
      for (int r = 0; r < 4; ++r) {
        int row = m0 + wr * 128 + mi * 16 + eq * 4 + r;
        int col = n0 + wc * 64 + ni * 16 + er;
        float v = acc[mi][ni][r] * scale;
        if (HAS_BIAS) v += bias[col];
        if (RELU) v = v > 0.f ? v : 0.f;
        if (QKV) {
          int which = col >> 10;       // 0=q, 1=k, 2=v
          int c2 = col & 1023;
          size_t ro = (size_t)row * 1024 + c2;
          int fslot = (which == 0) ? 2 : (which == 1) ? 1 : 3;  // d_out order: out,k,q,v
          __builtin_nontemporal_store(v, &Cf[(size_t)fslot * OUT_SLOT + ro]);
          Cb[(size_t)which * OUT_SLOT + ro] = f2bf(v);          // ws order: q,k,v
        } else {
          size_t idx = (size_t)z * cBatch + (size_t)row * N + col;
          if (WF32) Cf[idx] = v;
          if (WB16) Cb[idx] = f2bf(v);
        }
      }
    }
  }
}

// ---------------- row softmax, IN PLACE on bf16 scores [rows][2048] ----------------
__global__ __launch_bounds__(256) void k_softmax(unsigned short* __restrict__ sa) {
  __shared__ float red[4];
  const int row = blockIdx.x;
  const int tid = threadIdx.x;
  unsigned short* sr = sa + (size_t)row * Ss;
  ushort4 u0 = ((const ushort4*)sr)[tid];
  ushort4 u1 = ((const ushort4*)sr)[tid + 256];
  float e[8];
  e[0] = bf2f(u0.x); e[1] = bf2f(u0.y); e[2] = bf2f(u0.z); e[3] = bf2f(u0.w);
  e[4] = bf2f(u1.x); e[5] = bf2f(u1.y); e[6] = bf2f(u1.z); e[7] = bf2f(u1.w);
  float m = fmaxf(fmaxf(fmaxf(e[0], e[1]), fmaxf(e[2], e[3])),
                  fmaxf(fmaxf(e[4], e[5]), fmaxf(e[6], e[7])));
  for (int s = 1; s < 64; s <<= 1) m = fmaxf(m, __shfl_xor(m, s, 64));
  if ((tid & 63) == 0) red[tid >> 6] = m;
  __syncthreads();
  m = fmaxf(fmaxf(red[0], red[1]), fmaxf(red[2], red[3]));
  __syncthreads();
  float sum = 0.f;
#pragma unroll
  for (int j = 0; j < 8; ++j) { e[j] = __expf(e[j] - m); sum += e[j]; }
  for (int s = 1; s < 64; s <<= 1) sum += __shfl_xor(sum, s, 64);
  if ((tid & 63) == 0) red[tid >> 6] = sum;
  __syncthreads();
  sum = red[0] + red[1] + red[2] + red[3];
  float inv = 1.f / sum;
  ushort4 o0, o1;
  o0.x = f2bf(e[0] * inv); o0.y = f2bf(e[1] * inv);
  o0.z = f2bf(e[2] * inv); o0.w = f2bf(e[3] * inv);
  o1.x = f2bf(e[4] * inv); o1.y = f2bf(e[5] * inv);
  o1.z = f2bf(e[6] * inv); o1.w = f2bf(e[7] * inv);
  ((ushort4*)sr)[tid] = o0;
  ((ushort4*)sr)[tid + 256] = o1;
}

// ---------------- residual + LayerNorm ----------------
template <bool OUT_F32>
__global__ __launch_bounds__(256) void k_ln(const unsigned short* __restrict__ a,
                                            const unsigned short* __restrict__ bb,
                                            const float* __restrict__ gamma,
                                            const float* __restrict__ beta,
                                            void* __restrict__ outp) {
  __shared__ float red[4];
  const int row = blockIdx.x;
  const int tid = threadIdx.x;
  float v[4];
  ushort4 av = ((const ushort4*)(a + (size_t)row * Ee))[tid];
  v[0] = bf2f(av.x); v[1] = bf2f(av.y); v[2] = bf2f(av.z); v[3] = bf2f(av.w);
  ushort4 bv = ((const ushort4*)(bb + (size_t)row * Ee))[tid];
  v[0] += bf2f(bv.x); v[1] += bf2f(bv.y); v[2] += bf2f(bv.z); v[3] += bf2f(bv.w);
  float s = v[0] + v[1] + v[2] + v[3];
  float q = v[0] * v[0] + v[1] * v[1] + v[2] * v[2] + v[3] * v[3];
  for (int sh = 1; sh < 64; sh <<= 1) {
    s += __shfl_xor(s, sh, 64);
    q += __shfl_xor(q, sh, 64);
  }
  if ((tid & 63) == 0) red[tid >> 6] = s;
  __syncthreads();
  s = red[0] + red[1] + red[2] + red[3];
  __syncthreads();
  if ((tid & 63) == 0) red[tid >> 6] = q;
  __syncthreads();
  q = red[0] + red[1] + red[2] + red[3];
  float mu = s * (1.f / Ee);
  float var = q * (1.f / Ee) - mu * mu;
  float rinv = rsqrtf(var + 1e-5f);
  int c = tid * 4;
  float o0 = (v[0] - mu) * rinv * gamma[c + 0] + beta[c + 0];
  float o1 = (v[1] - mu) * rinv * gamma[c + 1] + beta[c + 1];
  float o2 = (v[2] - mu) * rinv * gamma[c + 2] + beta[c + 2];
  float o3 = (v[3] - mu) * rinv * gamma[c + 3] + beta[c + 3];
  if (OUT_F32) {
    f32x4 o = {o0, o1, o2, o3};
    __builtin_nontemporal_store(o, (f32x4*)((float*)outp + (size_t)row * Ee) + tid);
  } else {
    ushort4 o;
    o.x = f2bf(o0); o.y = f2bf(o1); o.z = f2bf(o2); o.w = f2bf(o3);
    ((ushort4*)((unsigned short*)outp + (size_t)row * Ee))[tid] = o;
  }
}

extern "C" void kernel_launch(void* const* d_in, const int* in_sizes, int n_in,
                              void* d_out, int out_size, void* d_ws, size_t ws_size,
                              hipStream_t stream) {
  const float* x = (const float*)d_in[0];
  const float* Wq = (const float*)d_in[1];
  const float* bq = (const float*)d_in[2];
  const float* Wk = (const float*)d_in[3];
  const float* bk = (const float*)d_in[4];
  const float* Wv = (const float*)d_in[5];
  const float* bv = (const float*)d_in[6];
  const float* g1 = (const float*)d_in[7];
  const float* be1 = (const float*)d_in[8];
  const float* W1 = (const float*)d_in[9];
  const float* b1 = (const float*)d_in[10];
  const float* W2 = (const float*)d_in[11];
  const float* b2 = (const float*)d_in[12];
  const float* g2 = (const float*)d_in[13];
  const float* be2 = (const float*)d_in[14];

  float* out = (float*)d_out;          // return order: (out, k, q, v), all f32

  char* ws = (char*)d_ws;
  unsigned short* xb    = (unsigned short*)(ws + 0);             // 33.6 MB
  unsigned short* WqkvT = (unsigned short*)(ws + 33554432ull);   // 6.3 MB [3072][1024]
  unsigned short* W1T   = (unsigned short*)(ws + 39845888ull);   // 8.4 MB  [F][E]
  unsigned short* W2T   = (unsigned short*)(ws + 48234496ull);   // 8.4 MB  [E][F]
  unsigned short* qb    = (unsigned short*)(ws + 56623104ull);   // 33.6 MB bf16 q (k,v contig)
  unsigned short* kb    = (unsigned short*)(ws + 90177536ull);   // 33.6 MB bf16 k
  unsigned short* vb    = (unsigned short*)(ws + 123731968ull);  // 33.6 MB bf16 v
  unsigned short* scb   = (unsigned short*)(ws + 157286400ull);  // 67.1 MB bf16 scores/attn
  unsigned short* vT    = (unsigned short*)(ws + 224395264ull);  // 33.6 MB
  float*          bqkv  = (float*)(ws + 257949696ull);           // 12 KB
  unsigned short* ao    = (unsigned short*)(ws + 56623104ull);   // reuse qb (dead after scores)
  unsigned short* hb    = (unsigned short*)(ws + 90177536ull);   // reuse kb (dead after scores)
  unsigned short* f1b   = (unsigned short*)(ws + 157286400ull);  // reuse scb+vT (dead)
  unsigned short* f2b   = (unsigned short*)(ws + 123731968ull);  // reuse vb (dead after transpose)

  dim3 tb(32, 8);
  // stage 0: conversions
  k_cvt_f32_bf16<<<2048, 256, 0, stream>>>(x, xb, M_TOK * Ee / 4);
  k_transpose_w<<<dim3(32, 32), tb, 0, stream>>>(Wq, WqkvT, Ee, Ee);
  k_transpose_w<<<dim3(32, 32), tb, 0, stream>>>(Wk, WqkvT + 1048576, Ee, Ee);
  k_transpose_w<<<dim3(32, 32), tb, 0, stream>>>(Wv, WqkvT + 2097152, Ee, Ee);
  k_transpose_w<<<dim3(128, 32), tb, 0, stream>>>(W1, W1T, Ee, Ff);
  k_transpose_w<<<dim3(32, 128), tb, 0, stream>>>(W2, W2T, Ff, Ee);
  k_concat3<<<12, 256, 0, stream>>>(bq, bk, bv, bqkv);
  // stage 1: fused q|k|v  (f32 -> d_out slots, bf16 -> ws) — 2-slot variant (2 blocks/CU)
  k_gemm256<true, true, true, true, false, true><<<dim3(64, 12, 1), 512, 0, stream>>>(
      xb, WqkvT, out, qb, bqkv, M_TOK, 3072, Ee, 0, 0, 0, 1.f);
  // stage 2: scores = q @ k^T / 32  (batched over 8) -> bf16
  k_gemm256<false, false, false, true, false, false><<<dim3(8, 8, 8), 512, 0, stream>>>(
      qb, kb, nullptr, scb, nullptr, Ss, Ss, Ee, (long)Ss * Ee, (long)Ss * Ee, (long)Ss * Ss,
      0.03125f);
  // stage 3: softmax rows, in place
  k_softmax<<<Bb * Ss, 256, 0, stream>>>(scb);
  // stage 4: vT then attn @ v
  k_transpose_v<<<dim3(32, 64, 8), tb, 0, stream>>>(vb, vT);
  k_gemm256<false, false, false, true, false, false><<<dim3(8, 4, 8), 512, 0, stream>>>(
      scb, vT, nullptr, ao, nullptr, Ss, Ee, Ss, (long)Ss * Ss, (long)Ee * Ss, (long)Ss * Ee, 1.f);
  // stage 5: LN1 -> h (bf16), x read as bf16 (xb)
  k_ln<false><<<M_TOK, 256, 0, stream>>>(xb, ao, g1, be1, hb);
  // stage 6: FFN
  k_gemm256<false, false, false, true, true, true><<<dim3(64, 16, 1), 512, 0, stream>>>(
      hb, W1T, nullptr, f1b, b1, M_TOK, Ff, Ee, 0, 0, 0, 1.f);
  k_gemm256<false, false, false, true, false, true><<<dim3(64, 4, 1), 512, 0, stream>>>(
      f1b, W2T, nullptr, f2b, b2, M_TOK, Ee, Ff, 0, 0, 0, 1.f);
  // stage 7: LN2 -> out (f32)
  k_ln<true><<<M_TOK, 256, 0, stream>>>(hb, f2b, g2, be2, out);
}

// Round 14
// 638.978 us; speedup vs baseline: 1.0446x; 1.0446x over previous
//
#include <hip/hip_runtime.h>
#include <hip/hip_bf16.h>
#include <stdint.h>

typedef __attribute__((ext_vector_type(8))) short s16x8;
typedef __attribute__((ext_vector_type(4))) float f32x4;

static constexpr int Bb = 8, Ss = 2048, Ee = 1024, Ff = 4096;
static constexpr int M_TOK = Bb * Ss;                      // 16384
static constexpr size_t OUT_SLOT = (size_t)M_TOK * Ee;     // elements per output tensor

__device__ inline unsigned short f2bf(float f) {
  unsigned int u = __float_as_uint(f);
  unsigned int r = (u + 0x7FFFu + ((u >> 16) & 1u)) >> 16;
  return (unsigned short)r;
}
__device__ inline float bf2f(unsigned short h) {
  return __uint_as_float(((unsigned int)h) << 16);
}

// direct HBM -> LDS, 16B per lane; lds dest = wave-uniform base + lane*16
__device__ inline void gload16(const unsigned short* g, const unsigned short* l) {
  __builtin_amdgcn_global_load_lds(
      (const __attribute__((address_space(1))) void*)g,
      (__attribute__((address_space(3))) void*)(unsigned short*)l, 16, 0, 0);
}

// ---------------- elementwise f32 -> bf16 ----------------
__global__ __launch_bounds__(256) void k_cvt_f32_bf16(const float* __restrict__ in,
                                                      unsigned short* __restrict__ out, int n4) {
  int i = blockIdx.x * blockDim.x + threadIdx.x;
  int stride = gridDim.x * blockDim.x;
  for (; i < n4; i += stride) {
    float4 v = ((const float4*)in)[i];
    ushort4 o;
    o.x = f2bf(v.x); o.y = f2bf(v.y); o.z = f2bf(v.z); o.w = f2bf(v.w);
    ((ushort4*)out)[i] = o;
  }
}

// ---------------- concat 3 bias vectors [1024] -> [3072] ----------------
__global__ __launch_bounds__(256) void k_concat3(const float* __restrict__ a,
                                                 const float* __restrict__ b,
                                                 const float* __restrict__ c,
                                                 float* __restrict__ out) {
  int i = blockIdx.x * 256 + threadIdx.x;
  const float* src = (i < 1024) ? a : (i < 2048) ? b : c;
  out[i] = src[i & 1023];
}

// ---------------- transpose+convert W[R][C] f32 -> WT[C][R] bf16 ----------------
__global__ __launch_bounds__(256) void k_transpose_w(const float* __restrict__ in,
                                                     unsigned short* __restrict__ out,
                                                     int R, int C) {
  __shared__ float t[32][33];
  int c0 = blockIdx.x * 32, r0 = blockIdx.y * 32;
  int tx = threadIdx.x, ty = threadIdx.y;
  for (int i = ty; i < 32; i += 8)
    t[i][tx] = in[(size_t)(r0 + i) * C + c0 + tx];
  __syncthreads();
  for (int i = ty; i < 32; i += 8)
    out[(size_t)(c0 + i) * R + r0 + tx] = f2bf(t[tx][i]);
}

// ---------------- batched 1024x1024 transpose for Wq/Wk/Wv (z selects) ----------------
__global__ __launch_bounds__(256) void k_transpose_w3(const float* __restrict__ w0,
                                                      const float* __restrict__ w1,
                                                      const float* __restrict__ w2,
                                                      unsigned short* __restrict__ out) {
  __shared__ float t[32][33];
  const int z = blockIdx.z;
  const float* in = (z == 0) ? w0 : (z == 1) ? w1 : w2;
  unsigned short* o = out + (size_t)z * Ee * Ee;
  int c0 = blockIdx.x * 32, r0 = blockIdx.y * 32;
  int tx = threadIdx.x, ty = threadIdx.y;
  for (int i = ty; i < 32; i += 8)
    t[i][tx] = in[(size_t)(r0 + i) * Ee + c0 + tx];
  __syncthreads();
  for (int i = ty; i < 32; i += 8)
    o[(size_t)(c0 + i) * Ee + r0 + tx] = f2bf(t[tx][i]);
}

// ---------------- per-batch transpose v[S][E] bf16 -> vT[E][S] bf16 ----------------
__global__ __launch_bounds__(256) void k_transpose_v(const unsigned short* __restrict__ v,
                                                     unsigned short* __restrict__ vT) {
  __shared__ unsigned short t[32][33];
  int b = blockIdx.z;
  const unsigned short* in = v + (size_t)b * Ss * Ee;
  unsigned short* out = vT + (size_t)b * Ee * Ss;
  int c0 = blockIdx.x * 32, r0 = blockIdx.y * 32;  // c over E, r over S
  int tx = threadIdx.x, ty = threadIdx.y;
  for (int i = ty; i < 32; i += 8)
    t[i][tx] = in[(size_t)(r0 + i) * Ee + c0 + tx];
  __syncthreads();
  for (int i = ty; i < 32; i += 8)
    out[(size_t)(c0 + i) * Ss + r0 + tx] = t[tx][i];
}

// ---------------- 256x256 pipelined bf16 GEMM (16x16x32 MFMA, 2 barriers/tile) ----------------
// 8 waves (2M x 4N), per-wave 128x64 output (8x4 frags). LDS: 4-slot ring of BK=32 (128 KiB).
// Per tile t:
//   reads0 (4 B-frags + 4 A-frags, slot t) | STAGE_A(t+3) -> vmcnt(6|4|0) -> BAR ->
//   MFMA mi0-3 (16) [reads1 (4 A-frags) + STAGE_B(t+3) float into this cluster] -> BAR ->
//   MFMA mi4-7 (16)
// Safety: slot t landing proven by tile t-1's vmcnt(6); STAGE(t+3) overwrites slot t-1,
// whose last reader finished before the preceding barrier (skew bound = 1 sub-phase).
// Swizzle: chunk c -> c ^ ((r>>1)&3): measured 0 bank conflicts.
// QKV mode: N=3072 fused q|k|v; epilogue demuxes by col>>10, f32 stores nontemporal.
template <bool QKV, bool WF32, bool WB16, bool RELU, bool HAS_BIAS>
__global__ __launch_bounds__(512, 2) void k_gemm256(const unsigned short* __restrict__ A,
                                                    const unsigned short* __restrict__ Bt,
                                                    float* __restrict__ Cf,
                                                    unsigned short* __restrict__ Cb,
                                                    const float* __restrict__ bias,
                                                    int M, int N, int K,
                                                    long aBatch, long bBatch, long cBatch,
                                                    float scale) {
  __shared__ unsigned short lds[4][2][256 * 32];  // [slot][A|B] 128 KiB
  const int tid = threadIdx.x;
  const int lane = tid & 63;
  const int wid = tid >> 6;              // 0..7
  const int wr = wid >> 2, wc = wid & 3; // 2 x 4 wave grid

  // T1 + L2 locality: XCD gets a contiguous chunk of a (4-m-wide, n-fast) global order.
  const int gx = gridDim.x, gy = gridDim.y;
  const int nwg = gx * gy;
  const int id = blockIdx.y * gx + blockIdx.x;
  const int qq = nwg >> 3;
  const int s = (id & 7) * qq + (id >> 3);  // global order index
  const int g4 = s / (gy * 4);
  const int r4 = s - g4 * gy * 4;
  const int m0 = (g4 * 4 + (r4 & 3)) * 256;
  const int n0 = (r4 >> 2) * 256;
  const int z = blockIdx.z;
  A += (size_t)z * aBatch;
  Bt += (size_t)z * bBatch;

  // staging: dest elem = j*4096 + tid*8 -> row = j*128 + tid/4, chunk_dst = tid&3.
  // source chunk = chunk_dst ^ ((row>>1)&3); (row>>1)&3 == (tid>>3)&3 for both j.
  const int srow = tid >> 2;
  const int csrc = (tid & 3) ^ ((tid >> 3) & 3);
  const unsigned short* ga0 = A + (size_t)(m0 + srow) * K + csrc * 8;
  const unsigned short* ga1 = A + (size_t)(m0 + 128 + srow) * K + csrc * 8;
  const unsigned short* gb0 = Bt + (size_t)(n0 + srow) * K + csrc * 8;
  const unsigned short* gb1 = Bt + (size_t)(n0 + 128 + srow) * K + csrc * 8;
  const int waveDst = (wid << 9);  // wave-uniform LDS elem offset; +lane*8 implicit

  auto STAGE_A = [&](int step) {
    const int slot = step & 3;
    const size_t ko = (size_t)step << 5;
    const unsigned short* la = &lds[slot][0][0];
    gload16(ga0 + ko, la + waveDst);
    gload16(ga1 + ko, la + 4096 + waveDst);
  };
  auto STAGE_B = [&](int step) {
    const int slot = step & 3;
    const size_t ko = (size_t)step << 5;
    const unsigned short* lb = &lds[slot][1][0];
    gload16(gb0 + ko, lb + waveDst);
    gload16(gb1 + ko, lb + 4096 + waveDst);
  };

  f32x4 acc[8][4] = {};
  const int fr = lane & 15;
  const int cc = ((lane >> 4) ^ ((fr >> 1) & 3)) * 8;  // swizzled chunk elem offset
  const int nt = K >> 5;

  // prologue: stage tiles 0,1,2; wait tile 0 (oldest 4 of 12)
  STAGE_A(0); STAGE_B(0); STAGE_A(1); STAGE_B(1); STAGE_A(2); STAGE_B(2);
  asm volatile("s_waitcnt vmcnt(8)" ::: "memory");
  __builtin_amdgcn_s_barrier();
  asm volatile("" ::: "memory");

  for (int t = 0; t < nt; ++t) {
    const int slot = t & 3;
    const unsigned short* la = &lds[slot][0][0];
    const unsigned short* lb = &lds[slot][1][0];
    s16x8 ra[4], rb[4], ra2[4];
    // reads0: all B + A mi0-3 (slot t); stage A(t+3); vmcnt once per tile
#pragma unroll
    for (int ni = 0; ni < 4; ++ni)
      rb[ni] = *(const s16x8*)(lb + ((wc * 64 + ni * 16 + fr) * 32 + cc));
#pragma unroll
    for (int mi = 0; mi < 4; ++mi)
      ra[mi] = *(const s16x8*)(la + ((wr * 128 + mi * 16 + fr) * 32 + cc));
    if (t + 3 < nt) {
      STAGE_A(t + 3);
      asm volatile("s_waitcnt vmcnt(6)" ::: "memory");   // tile t+1 fully landed
    } else if (t + 2 < nt) {
      asm volatile("s_waitcnt vmcnt(4)" ::: "memory");
    } else {
      asm volatile("s_waitcnt vmcnt(0)" ::: "memory");
    }
    __builtin_amdgcn_s_barrier();
    asm volatile("" ::: "memory");
    // MFMA cluster 0; reads1 + STAGE_B may interleave into its shadow
    __builtin_amdgcn_s_setprio(1);
#pragma unroll
    for (int mi = 0; mi < 4; ++mi)
#pragma unroll
      for (int ni = 0; ni < 4; ++ni)
        acc[mi][ni] = __builtin_amdgcn_mfma_f32_16x16x32_bf16(ra[mi], rb[ni], acc[mi][ni], 0, 0, 0);
#pragma unroll
    for (int mi = 0; mi < 4; ++mi)
      ra2[mi] = *(const s16x8*)(la + ((wr * 128 + (mi + 4) * 16 + fr) * 32 + cc));
    if (t + 3 < nt) STAGE_B(t + 3);
    __builtin_amdgcn_s_setprio(0);
    __builtin_amdgcn_s_barrier();
    asm volatile("" ::: "memory");
    __builtin_amdgcn_s_setprio(1);
#pragma unroll
    for (int mi = 0; mi < 4; ++mi)
#pragma unroll
      for (int ni = 0; ni < 4; ++ni)
        acc[mi + 4][ni] = __builtin_amdgcn_mfma_f32_16x16x32_bf16(ra2[mi], rb[ni], acc[mi + 4][ni], 0, 0, 0);
    __builtin_amdgcn_s_setprio(0);
  }

  // epilogue: D mapping col=lane&15, row=(lane>>4)*4+reg  [verified m89]
  const int er = lane & 15, eq = lane >> 4;
#pragma unroll
  for (int mi = 0; mi < 8; ++mi) {
#pragma unroll
    for (int ni = 0; ni < 4; ++ni) {
#pragma unroll
      for (int r = 0; r < 4; ++r) {
        int row = m0 + wr * 128 + mi * 16 + eq * 4 + r;
        int col = n0 + wc * 64 + ni * 16 + er;
        float v = acc[mi][ni][r] * scale;
        if (HAS_BIAS) v += bias[col];
        if (RELU) v = v > 0.f ? v : 0.f;
        if (QKV) {
          int which = col >> 10;       // 0=q, 1=k, 2=v
          int c2 = col & 1023;
          size_t ro = (size_t)row * 1024 + c2;
          int fslot = (which == 0) ? 2 : (which == 1) ? 1 : 3;  // d_out order: out,k,q,v
          __builtin_nontemporal_store(v, &Cf[(size_t)fslot * OUT_SLOT + ro]);
          Cb[(size_t)which * OUT_SLOT + ro] = f2bf(v);          // ws order: q,k,v
        } else {
          size_t idx = (size_t)z * cBatch + (size_t)row * N + col;
          if (WF32) Cf[idx] = v;
          if (WB16) Cb[idx] = f2bf(v);
        }
      }
    }
  }
}

// ---------------- row softmax, IN PLACE on bf16 scores [rows][2048] ----------------
__global__ __launch_bounds__(256) void k_softmax(unsigned short* __restrict__ sa) {
  __shared__ float red[4];
  const int row = blockIdx.x;
  const int tid = threadIdx.x;
  unsigned short* sr = sa + (size_t)row * Ss;
  ushort4 u0 = ((const ushort4*)sr)[tid];
  ushort4 u1 = ((const ushort4*)sr)[tid + 256];
  float e[8];
  e[0] = bf2f(u0.x); e[1] = bf2f(u0.y); e[2] = bf2f(u0.z); e[3] = bf2f(u0.w);
  e[4] = bf2f(u1.x); e[5] = bf2f(u1.y); e[6] = bf2f(u1.z); e[7] = bf2f(u1.w);
  float m = fmaxf(fmaxf(fmaxf(e[0], e[1]), fmaxf(e[2], e[3])),
                  fmaxf(fmaxf(e[4], e[5]), fmaxf(e[6], e[7])));
  for (int s = 1; s < 64; s <<= 1) m = fmaxf(m, __shfl_xor(m, s, 64));
  if ((tid & 63) == 0) red[tid >> 6] = m;
  __syncthreads();
  m = fmaxf(fmaxf(red[0], red[1]), fmaxf(red[2], red[3]));
  __syncthreads();
  float sum = 0.f;
#pragma unroll
  for (int j = 0; j < 8; ++j) { e[j] = __expf(e[j] - m); sum += e[j]; }
  for (int s = 1; s < 64; s <<= 1) sum += __shfl_xor(sum, s, 64);
  if ((tid & 63) == 0) red[tid >> 6] = sum;
  __syncthreads();
  sum = red[0] + red[1] + red[2] + red[3];
  float inv = 1.f / sum;
  ushort4 o0, o1;
  o0.x = f2bf(e[0] * inv); o0.y = f2bf(e[1] * inv);
  o0.z = f2bf(e[2] * inv); o0.w = f2bf(e[3] * inv);
  o1.x = f2bf(e[4] * inv); o1.y = f2bf(e[5] * inv);
  o1.z = f2bf(e[6] * inv); o1.w = f2bf(e[7] * inv);
  ((ushort4*)sr)[tid] = o0;
  ((ushort4*)sr)[tid + 256] = o1;
}

// ---------------- residual + LayerNorm ----------------
template <bool OUT_F32>
__global__ __launch_bounds__(256) void k_ln(const unsigned short* __restrict__ a,
                                            const unsigned short* __restrict__ bb,
                                            const float* __restrict__ gamma,
                                            const float* __restrict__ beta,
                                            void* __restrict__ outp) {
  __shared__ float red[4];
  const int row = blockIdx.x;
  const int tid = threadIdx.x;
  float v[4];
  ushort4 av = ((const ushort4*)(a + (size_t)row * Ee))[tid];
  v[0] = bf2f(av.x); v[1] = bf2f(av.y); v[2] = bf2f(av.z); v[3] = bf2f(av.w);
  ushort4 bv = ((const ushort4*)(bb + (size_t)row * Ee))[tid];
  v[0] += bf2f(bv.x); v[1] += bf2f(bv.y); v[2] += bf2f(bv.z); v[3] += bf2f(bv.w);
  float s = v[0] + v[1] + v[2] + v[3];
  float q = v[0] * v[0] + v[1] * v[1] + v[2] * v[2] + v[3] * v[3];
  for (int sh = 1; sh < 64; sh <<= 1) {
    s += __shfl_xor(s, sh, 64);
    q += __shfl_xor(q, sh, 64);
  }
  if ((tid & 63) == 0) red[tid >> 6] = s;
  __syncthreads();
  s = red[0] + red[1] + red[2] + red[3];
  __syncthreads();
  if ((tid & 63) == 0) red[tid >> 6] = q;
  __syncthreads();
  q = red[0] + red[1] + red[2] + red[3];
  float mu = s * (1.f / Ee);
  float var = q * (1.f / Ee) - mu * mu;
  float rinv = rsqrtf(var + 1e-5f);
  int c = tid * 4;
  float o0 = (v[0] - mu) * rinv * gamma[c + 0] + beta[c + 0];
  float o1 = (v[1] - mu) * rinv * gamma[c + 1] + beta[c + 1];
  float o2 = (v[2] - mu) * rinv * gamma[c + 2] + beta[c + 2];
  float o3 = (v[3] - mu) * rinv * gamma[c + 3] + beta[c + 3];
  if (OUT_F32) {
    f32x4 o = {o0, o1, o2, o3};
    __builtin_nontemporal_store(o, (f32x4*)((float*)outp + (size_t)row * Ee) + tid);
  } else {
    ushort4 o;
    o.x = f2bf(o0); o.y = f2bf(o1); o.z = f2bf(o2); o.w = f2bf(o3);
    ((ushort4*)((unsigned short*)outp + (size_t)row * Ee))[tid] = o;
  }
}

extern "C" void kernel_launch(void* const* d_in, const int* in_sizes, int n_in,
                              void* d_out, int out_size, void* d_ws, size_t ws_size,
                              hipStream_t stream) {
  const float* x = (const float*)d_in[0];
  const float* Wq = (const float*)d_in[1];
  const float* bq = (const float*)d_in[2];
  const float* Wk = (const float*)d_in[3];
  const float* bk = (const float*)d_in[4];
  const float* Wv = (const float*)d_in[5];
  const float* bv = (const float*)d_in[6];
  const float* g1 = (const float*)d_in[7];
  const float* be1 = (const float*)d_in[8];
  const float* W1 = (const float*)d_in[9];
  const float* b1 = (const float*)d_in[10];
  const float* W2 = (const float*)d_in[11];
  const float* b2 = (const float*)d_in[12];
  const float* g2 = (const float*)d_in[13];
  const float* be2 = (const float*)d_in[14];

  float* out = (float*)d_out;          // return order: (out, k, q, v), all f32

  char* ws = (char*)d_ws;
  unsigned short* xb    = (unsigned short*)(ws + 0);             // 33.6 MB
  unsigned short* WqkvT = (unsigned short*)(ws + 33554432ull);   // 6.3 MB [3072][1024]
  unsigned short* W1T   = (unsigned short*)(ws + 39845888ull);   // 8.4 MB  [F][E]
  unsigned short* W2T   = (unsigned short*)(ws + 48234496ull);   // 8.4 MB  [E][F]
  unsigned short* qb    = (unsigned short*)(ws + 56623104ull);   // 33.6 MB bf16 q (k,v contig)
  unsigned short* kb    = (unsigned short*)(ws + 90177536ull);   // 33.6 MB bf16 k
  unsigned short* vb    = (unsigned short*)(ws + 123731968ull);  // 33.6 MB bf16 v
  unsigned short* scb   = (unsigned short*)(ws + 157286400ull);  // 67.1 MB bf16 scores/attn
  unsigned short* vT    = (unsigned short*)(ws + 224395264ull);  // 33.6 MB
  float*          bqkv  = (float*)(ws + 257949696ull);           // 12 KB
  unsigned short* ao    = (unsigned short*)(ws + 56623104ull);   // reuse qb (dead after scores)
  unsigned short* hb    = (unsigned short*)(ws + 90177536ull);   // reuse kb (dead after scores)
  unsigned short* f1b   = (unsigned short*)(ws + 157286400ull);  // reuse scb+vT (dead)
  unsigned short* f2b   = (unsigned short*)(ws + 123731968ull);  // reuse vb (dead after transpose)

  dim3 tb(32, 8);
  // stage 0: conversions
  k_cvt_f32_bf16<<<2048, 256, 0, stream>>>(x, xb, M_TOK * Ee / 4);
  k_transpose_w3<<<dim3(32, 32, 3), tb, 0, stream>>>(Wq, Wk, Wv, WqkvT);
  k_transpose_w<<<dim3(128, 32), tb, 0, stream>>>(W1, W1T, Ee, Ff);
  k_transpose_w<<<dim3(32, 128), tb, 0, stream>>>(W2, W2T, Ff, Ee);
  k_concat3<<<12, 256, 0, stream>>>(bq, bk, bv, bqkv);
  // stage 1: fused q|k|v  (f32 -> d_out slots, bf16 -> ws)
  k_gemm256<true, true, true, false, true><<<dim3(64, 12, 1), 512, 0, stream>>>(
      xb, WqkvT, out, qb, bqkv, M_TOK, 3072, Ee, 0, 0, 0, 1.f);
  // stage 2: scores = q @ k^T / 32  (batched over 8) -> bf16
  k_gemm256<false, false, true, false, false><<<dim3(8, 8, 8), 512, 0, stream>>>(
      qb, kb, nullptr, scb, nullptr, Ss, Ss, Ee, (long)Ss * Ee, (long)Ss * Ee, (long)Ss * Ss,
      0.03125f);
  // stage 3: softmax rows, in place
  k_softmax<<<Bb * Ss, 256, 0, stream>>>(scb);
  // stage 4: vT then attn @ v
  k_transpose_v<<<dim3(32, 64, 8), tb, 0, stream>>>(vb, vT);
  k_gemm256<false, false, true, false, false><<<dim3(8, 4, 8), 512, 0, stream>>>(
      scb, vT, nullptr, ao, nullptr, Ss, Ee, Ss, (long)Ss * Ss, (long)Ee * Ss, (long)Ss * Ee, 1.f);
  // stage 5: LN1 -> h (bf16), x read as bf16 (xb)
  k_ln<false><<<M_TOK, 256, 0, stream>>>(xb, ao, g1, be1, hb);
  // stage 6: FFN
  k_gemm256<false, false, true, true, true><<<dim3(64, 16, 1), 512, 0, stream>>>(
      hb, W1T, nullptr, f1b, b1, M_TOK, Ff, Ee, 0, 0, 0, 1.f);
  k_gemm256<false, false, true, false, true><<<dim3(64, 4, 1), 512, 0, stream>>>(
      f1b, W2T, nullptr, f2b, b2, M_TOK, Ee, Ff, 0, 0, 0, 1.f);
  // stage 7: LN2 -> out (f32)
  k_ln<true><<<M_TOK, 256, 0, stream>>>(hb, f2b, g2, be2, out);
}